// Round 20
// baseline (124.781 us; speedup 1.0000x reference)
//
#include <hip/hip_runtime.h>

#define N_NODES 100000
#define N_EDGES 1600000
#define IN_DIM  128
#define HID_DIM 64
#define OUT_DIM 40

#define BUK_SHIFT 9
#define NBUK ((N_NODES + (1 << BUK_SHIFT) - 1) >> BUK_SHIFT)  // 196
#define CAP 12288                                             // edges per bucket slot
#define PART_CHUNK 4096
#define PART_EPT 16     // PART_CHUNK / 256
#define NCH ((N_EDGES + PART_CHUNK - 1) / PART_CHUNK)         // 391
#define MG_BLOCKS ((N_NODES + 127) / 128)                     // 782
#define MERGE_BLOCKS (NCH + MG_BLOCKS + 2)                    // partA + GEMM1 + packW2

typedef unsigned short ushort;
typedef unsigned int uint;
typedef __attribute__((ext_vector_type(8))) short bf16x8;
typedef __attribute__((ext_vector_type(4))) float f32x4;

// float -> bf16 bits, round-to-nearest-even
__device__ __forceinline__ ushort f2bf(float x) {
    uint u = __float_as_uint(x);
    uint r = ((u >> 16) & 1u) + 0x7fffu;
    return (ushort)((u + r) >> 16);
}

// ---------------- merged: partA (blk 0..390) + mgemm1 (391..1172) + packW2 (1173..1174) ----
// All branches mutually independent. partA uses RELATIVE cursors (zeroed by hipMemsetAsync).
__global__ __launch_bounds__(256) void merged_kernel(const int* __restrict__ src,
                                                     const int* __restrict__ dst,
                                                     int* __restrict__ cursorA,
                                                     uint* __restrict__ buk,
                                                     const float* __restrict__ W1,
                                                     const float* __restrict__ W2,
                                                     ushort* __restrict__ Wb2,
                                                     const float* __restrict__ X,
                                                     ushort* __restrict__ ts1, int M) {
    const int blk = blockIdx.x;
    const int t = threadIdx.x;
    if (blk < NCH) {
        __shared__ int hist[NBUK];
        __shared__ int base[NBUK];
        const int e0 = blk * PART_CHUNK;
        for (int i = t; i < NBUK; i += 256) hist[i] = 0;
        __syncthreads();
        int mys[PART_EPT], myd[PART_EPT];
#pragma unroll
        for (int i = 0; i < PART_EPT; ++i) {
            int e = e0 + t + i * 256;
            if (e < N_EDGES) {
                mys[i] = src[e];
                myd[i] = dst[e];
                atomicAdd(&hist[myd[i] >> BUK_SHIFT], 1);
            } else {
                myd[i] = -1;
            }
        }
        __syncthreads();
        for (int i = t; i < NBUK; i += 256)
            base[i] = (hist[i] > 0) ? atomicAdd(&cursorA[i], hist[i]) : 0;
        __syncthreads();
        for (int i = t; i < NBUK; i += 256) hist[i] = 0;
        __syncthreads();
#pragma unroll
        for (int i = 0; i < PART_EPT; ++i) {
            if (myd[i] >= 0) {
                int b = myd[i] >> BUK_SHIFT;
                int pos = b * CAP + base[b] + atomicAdd(&hist[b], 1);
                buk[pos] = (uint)mys[i] | ((uint)(myd[i] & 511) << 17);
            }
        }
    } else if (blk < NCH + MG_BLOCKS) {
        // ---- mgemm1: ts1 = X @ W1 (bf16, UNSCALED; dis applied in fused64) ----
        __shared__ ushort wlds[16 * 64 * 8];   // 16 KB
        const int gblk = blk - NCH;
        const int wave = t >> 6;
        const int lane = t & 63;
        const int la = lane & 15, lb = lane >> 4;

#pragma unroll
        for (int i = 0; i < 4; ++i) {
            int f = (t >> 6) + i * 4;         // 0..15
            int ks = f >> 2, ct = f & 3;
            int c = ct * 16 + la;
            int kb = ks * 32 + (lb << 3);
            ushort* wp = &wlds[(f * 64 + lane) * 8];
#pragma unroll
            for (int j = 0; j < 8; ++j)
                wp[j] = f2bf(W1[(kb + j) * HID_DIM + c]);
        }
        __syncthreads();

        const int r0 = gblk * 128 + wave * 32;
        f32x4 acc[2][4];
#pragma unroll
        for (int i = 0; i < 2; ++i)
#pragma unroll
            for (int j = 0; j < 4; ++j)
#pragma unroll
                for (int r = 0; r < 4; ++r) acc[i][j][r] = 0.0f;

        int ra0 = r0 + la;       if (ra0 >= M) ra0 = M - 1;
        int ra1 = r0 + 16 + la;  if (ra1 >= M) ra1 = M - 1;
        const float* xp0 = X + (long long)ra0 * IN_DIM + lb * 8;
        const float* xp1 = X + (long long)ra1 * IN_DIM + lb * 8;
        const bf16x8* wb = (const bf16x8*)wlds;

#pragma unroll
        for (int ks = 0; ks < 4; ++ks) {
            float4 x00 = *(const float4*)(xp0 + ks * 32);
            float4 x01 = *(const float4*)(xp0 + ks * 32 + 4);
            float4 x10 = *(const float4*)(xp1 + ks * 32);
            float4 x11 = *(const float4*)(xp1 + ks * 32 + 4);
            bf16x8 a0, a1;
            a0[0] = (short)f2bf(x00.x); a0[1] = (short)f2bf(x00.y);
            a0[2] = (short)f2bf(x00.z); a0[3] = (short)f2bf(x00.w);
            a0[4] = (short)f2bf(x01.x); a0[5] = (short)f2bf(x01.y);
            a0[6] = (short)f2bf(x01.z); a0[7] = (short)f2bf(x01.w);
            a1[0] = (short)f2bf(x10.x); a1[1] = (short)f2bf(x10.y);
            a1[2] = (short)f2bf(x10.z); a1[3] = (short)f2bf(x10.w);
            a1[4] = (short)f2bf(x11.x); a1[5] = (short)f2bf(x11.y);
            a1[6] = (short)f2bf(x11.z); a1[7] = (short)f2bf(x11.w);
#pragma unroll
            for (int ct = 0; ct < 4; ++ct) {
                bf16x8 b = wb[(ks * 4 + ct) * 64 + lane];
                acc[0][ct] = __builtin_amdgcn_mfma_f32_16x16x32_bf16(a0, b, acc[0][ct], 0, 0, 0);
                acc[1][ct] = __builtin_amdgcn_mfma_f32_16x16x32_bf16(a1, b, acc[1][ct], 0, 0, 0);
            }
        }

#pragma unroll
        for (int rt = 0; rt < 2; ++rt)
#pragma unroll
            for (int r = 0; r < 4; ++r) {
                int row = r0 + rt * 16 + lb * 4 + r;
                if (row < M) {
#pragma unroll
                    for (int ct = 0; ct < 4; ++ct)
                        ts1[(long long)row * HID_DIM + ct * 16 + la] = f2bf(acc[rt][ct][r]);
                }
            }
    } else {
        int tt = (blk - NCH - MG_BLOCKS) * 256 + t;   // 0..511 (384 used)
        if (tt < 384) {
            int lane = tt & 63;
            int f = tt >> 6;          // 0..5
            int ks = f / 3, ct = f % 3;
            int c = ct * 16 + (lane & 15);
            int kb = ks * 32 + ((lane >> 4) << 3);
#pragma unroll
            for (int j = 0; j < 8; ++j)
                Wb2[tt * 8 + j] = (c < OUT_DIM) ? f2bf(W2[(kb + j) * OUT_DIM + c]) : 0;
        }
    }
}

// ---------------- per-bucket: degrees + rowbeg/rowend + dis + csr fill, all LDS -------------
__global__ __launch_bounds__(512) void bucket_kernel(const uint* __restrict__ buk,
                                                     const int* __restrict__ cursorA,
                                                     int* __restrict__ rowbeg,
                                                     int* __restrict__ rowend,
                                                     float* __restrict__ dis,
                                                     int* __restrict__ csr, int n) {
    __shared__ int cnt[512];
    __shared__ int pre[512];
    const int t = threadIdx.x;
    const int b = blockIdx.x;
    const int beg = b * CAP, end = b * CAP + cursorA[b];
    cnt[t] = 0;
    __syncthreads();
    for (int i = beg + t; i < end; i += 512)
        atomicAdd(&cnt[(buk[i] >> 17) & 511], 1);
    __syncthreads();
    const int c = cnt[t];
    pre[t] = c;
    __syncthreads();
    for (int off = 1; off < 512; off <<= 1) {
        int v = (t >= off) ? pre[t - off] : 0;
        __syncthreads();
        pre[t] += v;
        __syncthreads();
    }
    const int ex = pre[t] - c;
    const int v0 = (b << BUK_SHIFT) + t;
    if (v0 < n) {
        rowbeg[v0] = beg + ex;
        rowend[v0] = beg + ex + c;
        dis[v0] = rsqrtf((float)c + 1.0f);
    }
    __syncthreads();
    cnt[t] = beg + ex;
    __syncthreads();
    for (int i = beg + t; i < end; i += 512) {
        uint e = buk[i];
        int pos = atomicAdd(&cnt[(e >> 17) & 511], 1);
        csr[pos] = (int)(e & 0x1FFFFu);
    }
}

// ---------------- bf16 unpack helpers ----------------
__device__ __forceinline__ void add_bf8(float* acc, uint4 m) {
    acc[0] += __uint_as_float(m.x << 16);
    acc[1] += __uint_as_float(m.x & 0xffff0000u);
    acc[2] += __uint_as_float(m.y << 16);
    acc[3] += __uint_as_float(m.y & 0xffff0000u);
    acc[4] += __uint_as_float(m.z << 16);
    acc[5] += __uint_as_float(m.z & 0xffff0000u);
    acc[6] += __uint_as_float(m.w << 16);
    acc[7] += __uint_as_float(m.w & 0xffff0000u);
}

// acc += s * unpack(m)
__device__ __forceinline__ void fma_bf8(float* acc, uint4 m, float s) {
    acc[0] = fmaf(s, __uint_as_float(m.x << 16), acc[0]);
    acc[1] = fmaf(s, __uint_as_float(m.x & 0xffff0000u), acc[1]);
    acc[2] = fmaf(s, __uint_as_float(m.y << 16), acc[2]);
    acc[3] = fmaf(s, __uint_as_float(m.y & 0xffff0000u), acc[3]);
    acc[4] = fmaf(s, __uint_as_float(m.z << 16), acc[4]);
    acc[5] = fmaf(s, __uint_as_float(m.z & 0xffff0000u), acc[5]);
    acc[6] = fmaf(s, __uint_as_float(m.w << 16), acc[6]);
    acc[7] = fmaf(s, __uint_as_float(m.w & 0xffff0000u), acc[7]);
}

// 4-deep pipelined neighbor accumulation over base+stride rows (uint4 units)
__device__ __forceinline__ void gather_pipe4g(const uint4* __restrict__ bp, int stride,
                                              const int* __restrict__ csr,
                                              int beg, int end, float* acc) {
    int j = beg;
    if (j + 3 < end) {
        int c0 = csr[j], c1 = csr[j + 1], c2 = csr[j + 2], c3 = csr[j + 3];
        j += 4;
        for (; j + 3 < end; j += 4) {
            int n0 = csr[j], n1 = csr[j + 1], n2 = csr[j + 2], n3 = csr[j + 3];
            uint4 m0 = bp[c0 * stride];
            uint4 m1 = bp[c1 * stride];
            uint4 m2 = bp[c2 * stride];
            uint4 m3 = bp[c3 * stride];
            add_bf8(acc, m0); add_bf8(acc, m1); add_bf8(acc, m2); add_bf8(acc, m3);
            c0 = n0; c1 = n1; c2 = n2; c3 = n3;
        }
        uint4 m0 = bp[c0 * stride];
        uint4 m1 = bp[c1 * stride];
        uint4 m2 = bp[c2 * stride];
        uint4 m3 = bp[c3 * stride];
        add_bf8(acc, m0); add_bf8(acc, m1); add_bf8(acc, m2); add_bf8(acc, m3);
    }
    for (; j < end; ++j) add_bf8(acc, bp[csr[j] * stride]);
}

// 4-deep pipelined, per-neighbor dis scale (fused64 layer-1 gather; STRIDE=8 fixed)
__device__ __forceinline__ void gather_pipe4s(const uint4* __restrict__ tsv,
                                              const int* __restrict__ csr,
                                              const float* __restrict__ dis,
                                              int beg, int end, int q, float* acc) {
    int j = beg;
    if (j + 3 < end) {
        int c0 = csr[j], c1 = csr[j + 1], c2 = csr[j + 2], c3 = csr[j + 3];
        j += 4;
        for (; j + 3 < end; j += 4) {
            int n0 = csr[j], n1 = csr[j + 1], n2 = csr[j + 2], n3 = csr[j + 3];
            float d0 = dis[c0], d1 = dis[c1], d2 = dis[c2], d3 = dis[c3];
            uint4 m0 = tsv[c0 * 8 + q];
            uint4 m1 = tsv[c1 * 8 + q];
            uint4 m2 = tsv[c2 * 8 + q];
            uint4 m3 = tsv[c3 * 8 + q];
            fma_bf8(acc, m0, d0); fma_bf8(acc, m1, d1);
            fma_bf8(acc, m2, d2); fma_bf8(acc, m3, d3);
            c0 = n0; c1 = n1; c2 = n2; c3 = n3;
        }
        float d0 = dis[c0], d1 = dis[c1], d2 = dis[c2], d3 = dis[c3];
        uint4 m0 = tsv[c0 * 8 + q];
        uint4 m1 = tsv[c1 * 8 + q];
        uint4 m2 = tsv[c2 * 8 + q];
        uint4 m3 = tsv[c3 * 8 + q];
        fma_bf8(acc, m0, d0); fma_bf8(acc, m1, d1);
        fma_bf8(acc, m2, d2); fma_bf8(acc, m3, d3);
    }
    for (; j < end; ++j) { int u = csr[j]; fma_bf8(acc, tsv[u * 8 + q], dis[u]); }
}

// ---------------- fused: gather64 (dis[u]-scaled) -> LDS h -> MFMA GEMM2 -> ts2a/ts2b -------
// ts2a: cols 0-31, 64 B rows (one line per random read). ts2b: cols 32-39, 16 B rows
// (1.6 MB -> L2-resident in layer-2 gather).
__global__ __launch_bounds__(256) void fused64_kernel(const int* __restrict__ rowbeg,
                                                      const int* __restrict__ rowend,
                                                      const int* __restrict__ csr,
                                                      const ushort* __restrict__ ts,
                                                      const float* __restrict__ dis,
                                                      const float* __restrict__ b1,
                                                      const ushort* __restrict__ Wb2,
                                                      ushort* __restrict__ Y2a,
                                                      ushort* __restrict__ Y2b, int n) {
    __shared__ ushort hs[32][72];   // 144 B row stride
    const int t = threadIdx.x;
    const int vloc = t >> 3, q = t & 7;
    const int v = blockIdx.x * 32 + vloc;

    if (v < n) {
        const uint4* tsv = (const uint4*)ts;
        int beg = rowbeg[v], end = rowend[v];
        float dv = dis[v];
        float acc[8] = {0.f, 0.f, 0.f, 0.f, 0.f, 0.f, 0.f, 0.f};
        fma_bf8(acc, tsv[(long long)v * 8 + q], dv);   // self-loop: dis[v]*ts1[v]
        gather_pipe4s(tsv, csr, dis, beg, end, q, acc);

        float4 b0 = ((const float4*)b1)[q * 2];
        float4 bb = ((const float4*)b1)[q * 2 + 1];
        float r0 = fmaxf(acc[0] * dv + b0.x, 0.0f);
        float r1 = fmaxf(acc[1] * dv + b0.y, 0.0f);
        float r2 = fmaxf(acc[2] * dv + b0.z, 0.0f);
        float r3 = fmaxf(acc[3] * dv + b0.w, 0.0f);
        float r4 = fmaxf(acc[4] * dv + bb.x, 0.0f);
        float r5 = fmaxf(acc[5] * dv + bb.y, 0.0f);
        float r6 = fmaxf(acc[6] * dv + bb.z, 0.0f);
        float r7 = fmaxf(acc[7] * dv + bb.w, 0.0f);
        uint4 o;
        o.x = ((uint)f2bf(r1) << 16) | f2bf(r0);
        o.y = ((uint)f2bf(r3) << 16) | f2bf(r2);
        o.z = ((uint)f2bf(r5) << 16) | f2bf(r4);
        o.w = ((uint)f2bf(r7) << 16) | f2bf(r6);
        *(uint4*)&hs[vloc][q * 8] = o;
    } else {
        uint4 z = {0u, 0u, 0u, 0u};
        *(uint4*)&hs[vloc][q * 8] = z;
    }
    __syncthreads();

    if (t < 128) {
        const int wave = t >> 6;           // 0 or 1 -> 16-node tile
        const int lane = t & 63;
        const int la = lane & 15, fg = lane >> 4;
        bf16x8 a0 = *(const bf16x8*)&hs[wave * 16 + la][fg * 8];
        bf16x8 a1 = *(const bf16x8*)&hs[wave * 16 + la][32 + fg * 8];

        const bf16x8* wb = (const bf16x8*)Wb2;
        f32x4 dacc[3];
#pragma unroll
        for (int ct = 0; ct < 3; ++ct)
#pragma unroll
            for (int r = 0; r < 4; ++r) dacc[ct][r] = 0.0f;
#pragma unroll
        for (int ct = 0; ct < 3; ++ct) {
            dacc[ct] = __builtin_amdgcn_mfma_f32_16x16x32_bf16(a0, wb[ct * 64 + lane], dacc[ct], 0, 0, 0);
            dacc[ct] = __builtin_amdgcn_mfma_f32_16x16x32_bf16(a1, wb[(3 + ct) * 64 + lane], dacc[ct], 0, 0, 0);
        }

        const int rbase = blockIdx.x * 32 + wave * 16 + fg * 4;
#pragma unroll
        for (int r = 0; r < 4; ++r) {
            int row = rbase + r;
            if (row < n) {
                float dvr = dis[row];
                // cols 0-31 -> ts2a (64 B rows)
                Y2a[(long long)row * 32 + 0 * 16 + la] = f2bf(dacc[0][r] * dvr);
                Y2a[(long long)row * 32 + 1 * 16 + la] = f2bf(dacc[1][r] * dvr);
                // cols 32-39 -> ts2b (16 B rows); cols 40-47 dropped (never consumed)
                if (la < 8)
                    Y2b[(long long)row * 8 + la] = f2bf(dacc[2][r] * dvr);
            }
        }
    }
}

// ---------------- fused gather 40 + log_softmax: block=320 (64 nodes), 4-deep pipeline --------
// q<4 reads ts2a (stride 4 uint4); q==4 reads ts2b (stride 1, L2-resident).
__global__ __launch_bounds__(320) void gather40ls_kernel(const int* __restrict__ rowbeg,
                                                         const int* __restrict__ rowend,
                                                         const int* __restrict__ csr,
                                                         const ushort* __restrict__ ts2a,
                                                         const ushort* __restrict__ ts2b,
                                                         const float* __restrict__ dis,
                                                         const float* __restrict__ b,
                                                         float* __restrict__ out, int n) {
    __shared__ float smax[64][5];
    __shared__ float ssum[64][5];
    const int t = threadIdx.x;
    const int vloc = t / 5, q = t - vloc * 5;
    const int v = blockIdx.x * 64 + vloc;
    const bool active = (v < n);

    float r[8];
    if (active) {
        const uint4* bp;
        int stride;
        if (q < 4) { bp = (const uint4*)ts2a + q; stride = 4; }
        else       { bp = (const uint4*)ts2b;     stride = 1; }
        int beg = rowbeg[v], end = rowend[v];
        float acc[8];
        {
            uint4 m = bp[(long long)v * stride];
            acc[0] = __uint_as_float(m.x << 16);
            acc[1] = __uint_as_float(m.x & 0xffff0000u);
            acc[2] = __uint_as_float(m.y << 16);
            acc[3] = __uint_as_float(m.y & 0xffff0000u);
            acc[4] = __uint_as_float(m.z << 16);
            acc[5] = __uint_as_float(m.z & 0xffff0000u);
            acc[6] = __uint_as_float(m.w << 16);
            acc[7] = __uint_as_float(m.w & 0xffff0000u);
        }
        gather_pipe4g(bp, stride, csr, beg, end, acc);

        float dv = dis[v];
        float4 b0 = ((const float4*)b)[q * 2];
        float4 b1 = ((const float4*)b)[q * 2 + 1];
        r[0] = acc[0] * dv + b0.x;
        r[1] = acc[1] * dv + b0.y;
        r[2] = acc[2] * dv + b0.z;
        r[3] = acc[3] * dv + b0.w;
        r[4] = acc[4] * dv + b1.x;
        r[5] = acc[5] * dv + b1.y;
        r[6] = acc[6] * dv + b1.z;
        r[7] = acc[7] * dv + b1.w;
    } else {
#pragma unroll
        for (int i = 0; i < 8; ++i) r[i] = 0.0f;
    }

    float m = r[0];
#pragma unroll
    for (int i = 1; i < 8; ++i) m = fmaxf(m, r[i]);
    smax[vloc][q] = m;
    __syncthreads();
    float gm = fmaxf(fmaxf(fmaxf(smax[vloc][0], smax[vloc][1]), fmaxf(smax[vloc][2], smax[vloc][3])),
                     smax[vloc][4]);
    float s = 0.0f;
#pragma unroll
    for (int i = 0; i < 8; ++i) s += __expf(r[i] - gm);
    ssum[vloc][q] = s;
    __syncthreads();
    float tot = ssum[vloc][0] + ssum[vloc][1] + ssum[vloc][2] + ssum[vloc][3] + ssum[vloc][4];
    float c = gm + __logf(tot);

    if (active) {
        float* rp = out + (long long)v * OUT_DIM + q * 8;
        float4 o0 = { r[0] - c, r[1] - c, r[2] - c, r[3] - c };
        float4 o1 = { r[4] - c, r[5] - c, r[6] - c, r[7] - c };
        ((float4*)rp)[0] = o0;
        ((float4*)rp)[1] = o1;
    }
}

extern "C" void kernel_launch(void* const* d_in, const int* in_sizes, int n_in,
                              void* d_out, int out_size, void* d_ws, size_t ws_size,
                              hipStream_t stream) {
    const float* x  = (const float*)d_in[0];
    const int*   ei = (const int*)d_in[1];
    const float* W1 = (const float*)d_in[2];
    const float* b1 = (const float*)d_in[3];
    const float* W2 = (const float*)d_in[4];
    const float* b2 = (const float*)d_in[5];
    float* out = (float*)d_out;

    const int* src = ei;
    const int* dst = ei + N_EDGES;

    // workspace layout (bytes) — non-overlapping; csr/buk CAP-padded (196*12288*4 = 9.63 MB)
    char* ws = (char*)d_ws;
    int*    rowbeg  = (int*)ws;                         // [0, 400K)
    int*    rowend  = (int*)(ws + (512 << 10));         // [512K, +400K)
    float*  dis     = (float*)(ws + (1024 << 10));      // [1024K, +400K)
    int*    cursorA = (int*)(ws + (1536 << 10));        // 784 B (RELATIVE counts)
    ushort* Wb2     = (ushort*)(ws + (1540 << 10));     // 6 KB
    int*    csr     = (int*)(ws + (2048 << 10));        // 9.63 MB
    char*   p       = ws + (12288 << 10);               // 12 MB
    ushort* ts1     = (ushort*)p;                       // 12.8 MB (bf16 [M][64], unscaled XW1)
    ushort* ts2a    = (ushort*)(p + 12800000);          // 6.4 MB (bf16 [M][32], cols 0-31)
    ushort* ts2b    = (ushort*)(p + 19200000);          // 1.6 MB (bf16 [M][8],  cols 32-39)
    uint*   buk     = (uint*)(p + 20800000);            // 9.63 MB

    // zero relative bucket cursors, then merged partA + GEMM1 + packW2 (co-scheduled)
    hipMemsetAsync(cursorA, 0, NBUK * sizeof(int), stream);
    merged_kernel<<<MERGE_BLOCKS, 256, 0, stream>>>(src, dst, cursorA, buk, W1, W2, Wb2,
                                                    x, ts1, N_NODES);

    // per-bucket CSR build
    bucket_kernel<<<NBUK, 512, 0, stream>>>(buk, cursorA, rowbeg, rowend, dis, csr, N_NODES);

    // fused: gather64 (dis-folded) + relu/bias -> LDS -> GEMM2 -> ts2a/ts2b
    fused64_kernel<<<(N_NODES + 31) / 32, 256, 0, stream>>>(rowbeg, rowend, csr, ts1, dis, b1,
                                                            Wb2, ts2a, ts2b, N_NODES);

    // layer 2 gather + log_softmax (split ts2 reads: 64 B line + L2-resident tail)
    gather40ls_kernel<<<(N_NODES + 63) / 64, 320, 0, stream>>>(rowbeg, rowend, csr, ts2a, ts2b,
                                                               dis, b2, out, N_NODES);
}

// Round 21
// 119.265 us; speedup vs baseline: 1.0462x; 1.0462x over previous
//
#include <hip/hip_runtime.h>

#define N_NODES 100000
#define N_EDGES 1600000
#define IN_DIM  128
#define HID_DIM 64
#define OUT_DIM 40

#define BUK_SHIFT 9
#define NBUK ((N_NODES + (1 << BUK_SHIFT) - 1) >> BUK_SHIFT)  // 196
#define CAP 12288                                             // edges per bucket slot
#define PART_CHUNK 4096
#define PART_EPT 16     // PART_CHUNK / 256
#define NCH ((N_EDGES + PART_CHUNK - 1) / PART_CHUNK)         // 391
#define MG_BLOCKS ((N_NODES + 127) / 128)                     // 782
#define MERGE_BLOCKS (NCH + MG_BLOCKS + 2)                    // partA + GEMM1 + packW2

typedef unsigned short ushort;
typedef unsigned int uint;
typedef __attribute__((ext_vector_type(8))) short bf16x8;
typedef __attribute__((ext_vector_type(4))) float f32x4;

// float -> bf16 bits, round-to-nearest-even
__device__ __forceinline__ ushort f2bf(float x) {
    uint u = __float_as_uint(x);
    uint r = ((u >> 16) & 1u) + 0x7fffu;
    return (ushort)((u + r) >> 16);
}

// ---------------- merged: partA (blk 0..390) + mgemm1 (391..1172) + packW2 (1173..1174) ----
// All branches mutually independent. partA uses RELATIVE cursors (zeroed by hipMemsetAsync).
__global__ __launch_bounds__(256) void merged_kernel(const int* __restrict__ src,
                                                     const int* __restrict__ dst,
                                                     int* __restrict__ cursorA,
                                                     uint* __restrict__ buk,
                                                     const float* __restrict__ W1,
                                                     const float* __restrict__ W2,
                                                     ushort* __restrict__ Wb2,
                                                     const float* __restrict__ X,
                                                     ushort* __restrict__ ts1, int M) {
    const int blk = blockIdx.x;
    const int t = threadIdx.x;
    if (blk < NCH) {
        __shared__ int hist[NBUK];
        __shared__ int base[NBUK];
        const int e0 = blk * PART_CHUNK;
        for (int i = t; i < NBUK; i += 256) hist[i] = 0;
        __syncthreads();
        int mys[PART_EPT], myd[PART_EPT];
#pragma unroll
        for (int i = 0; i < PART_EPT; ++i) {
            int e = e0 + t + i * 256;
            if (e < N_EDGES) {
                mys[i] = src[e];
                myd[i] = dst[e];
                atomicAdd(&hist[myd[i] >> BUK_SHIFT], 1);
            } else {
                myd[i] = -1;
            }
        }
        __syncthreads();
        for (int i = t; i < NBUK; i += 256)
            base[i] = (hist[i] > 0) ? atomicAdd(&cursorA[i], hist[i]) : 0;
        __syncthreads();
        for (int i = t; i < NBUK; i += 256) hist[i] = 0;
        __syncthreads();
#pragma unroll
        for (int i = 0; i < PART_EPT; ++i) {
            if (myd[i] >= 0) {
                int b = myd[i] >> BUK_SHIFT;
                int pos = b * CAP + base[b] + atomicAdd(&hist[b], 1);
                buk[pos] = (uint)mys[i] | ((uint)(myd[i] & 511) << 17);
            }
        }
    } else if (blk < NCH + MG_BLOCKS) {
        // ---- mgemm1: ts1 = X @ W1 (bf16, UNSCALED; dis applied in fused64) ----
        __shared__ ushort wlds[16 * 64 * 8];   // 16 KB
        const int gblk = blk - NCH;
        const int wave = t >> 6;
        const int lane = t & 63;
        const int la = lane & 15, lb = lane >> 4;

#pragma unroll
        for (int i = 0; i < 4; ++i) {
            int f = (t >> 6) + i * 4;         // 0..15
            int ks = f >> 2, ct = f & 3;
            int c = ct * 16 + la;
            int kb = ks * 32 + (lb << 3);
            ushort* wp = &wlds[(f * 64 + lane) * 8];
#pragma unroll
            for (int j = 0; j < 8; ++j)
                wp[j] = f2bf(W1[(kb + j) * HID_DIM + c]);
        }
        __syncthreads();

        const int r0 = gblk * 128 + wave * 32;
        f32x4 acc[2][4];
#pragma unroll
        for (int i = 0; i < 2; ++i)
#pragma unroll
            for (int j = 0; j < 4; ++j)
#pragma unroll
                for (int r = 0; r < 4; ++r) acc[i][j][r] = 0.0f;

        int ra0 = r0 + la;       if (ra0 >= M) ra0 = M - 1;
        int ra1 = r0 + 16 + la;  if (ra1 >= M) ra1 = M - 1;
        const float* xp0 = X + (long long)ra0 * IN_DIM + lb * 8;
        const float* xp1 = X + (long long)ra1 * IN_DIM + lb * 8;
        const bf16x8* wb = (const bf16x8*)wlds;

#pragma unroll
        for (int ks = 0; ks < 4; ++ks) {
            float4 x00 = *(const float4*)(xp0 + ks * 32);
            float4 x01 = *(const float4*)(xp0 + ks * 32 + 4);
            float4 x10 = *(const float4*)(xp1 + ks * 32);
            float4 x11 = *(const float4*)(xp1 + ks * 32 + 4);
            bf16x8 a0, a1;
            a0[0] = (short)f2bf(x00.x); a0[1] = (short)f2bf(x00.y);
            a0[2] = (short)f2bf(x00.z); a0[3] = (short)f2bf(x00.w);
            a0[4] = (short)f2bf(x01.x); a0[5] = (short)f2bf(x01.y);
            a0[6] = (short)f2bf(x01.z); a0[7] = (short)f2bf(x01.w);
            a1[0] = (short)f2bf(x10.x); a1[1] = (short)f2bf(x10.y);
            a1[2] = (short)f2bf(x10.z); a1[3] = (short)f2bf(x10.w);
            a1[4] = (short)f2bf(x11.x); a1[5] = (short)f2bf(x11.y);
            a1[6] = (short)f2bf(x11.z); a1[7] = (short)f2bf(x11.w);
#pragma unroll
            for (int ct = 0; ct < 4; ++ct) {
                bf16x8 b = wb[(ks * 4 + ct) * 64 + lane];
                acc[0][ct] = __builtin_amdgcn_mfma_f32_16x16x32_bf16(a0, b, acc[0][ct], 0, 0, 0);
                acc[1][ct] = __builtin_amdgcn_mfma_f32_16x16x32_bf16(a1, b, acc[1][ct], 0, 0, 0);
            }
        }

#pragma unroll
        for (int rt = 0; rt < 2; ++rt)
#pragma unroll
            for (int r = 0; r < 4; ++r) {
                int row = r0 + rt * 16 + lb * 4 + r;
                if (row < M) {
#pragma unroll
                    for (int ct = 0; ct < 4; ++ct)
                        ts1[(long long)row * HID_DIM + ct * 16 + la] = f2bf(acc[rt][ct][r]);
                }
            }
    } else {
        int tt = (blk - NCH - MG_BLOCKS) * 256 + t;   // 0..511 (384 used)
        if (tt < 384) {
            int lane = tt & 63;
            int f = tt >> 6;          // 0..5
            int ks = f / 3, ct = f % 3;
            int c = ct * 16 + (lane & 15);
            int kb = ks * 32 + ((lane >> 4) << 3);
#pragma unroll
            for (int j = 0; j < 8; ++j)
                Wb2[tt * 8 + j] = (c < OUT_DIM) ? f2bf(W2[(kb + j) * OUT_DIM + c]) : 0;
        }
    }
}

// ---------------- per-bucket: degrees + rowbeg/rowend + dis + csr fill, all LDS -------------
__global__ __launch_bounds__(512) void bucket_kernel(const uint* __restrict__ buk,
                                                     const int* __restrict__ cursorA,
                                                     int* __restrict__ rowbeg,
                                                     int* __restrict__ rowend,
                                                     float* __restrict__ dis,
                                                     int* __restrict__ csr, int n) {
    __shared__ int cnt[512];
    __shared__ int pre[512];
    const int t = threadIdx.x;
    const int b = blockIdx.x;
    const int beg = b * CAP, end = b * CAP + cursorA[b];
    cnt[t] = 0;
    __syncthreads();
    for (int i = beg + t; i < end; i += 512)
        atomicAdd(&cnt[(buk[i] >> 17) & 511], 1);
    __syncthreads();
    const int c = cnt[t];
    pre[t] = c;
    __syncthreads();
    for (int off = 1; off < 512; off <<= 1) {
        int v = (t >= off) ? pre[t - off] : 0;
        __syncthreads();
        pre[t] += v;
        __syncthreads();
    }
    const int ex = pre[t] - c;
    const int v0 = (b << BUK_SHIFT) + t;
    if (v0 < n) {
        rowbeg[v0] = beg + ex;
        rowend[v0] = beg + ex + c;
        dis[v0] = rsqrtf((float)c + 1.0f);
    }
    __syncthreads();
    cnt[t] = beg + ex;
    __syncthreads();
    for (int i = beg + t; i < end; i += 512) {
        uint e = buk[i];
        int pos = atomicAdd(&cnt[(e >> 17) & 511], 1);
        csr[pos] = (int)(e & 0x1FFFFu);
    }
}

// ---------------- bf16 unpack helpers ----------------
__device__ __forceinline__ void add_bf8(float* acc, uint4 m) {
    acc[0] += __uint_as_float(m.x << 16);
    acc[1] += __uint_as_float(m.x & 0xffff0000u);
    acc[2] += __uint_as_float(m.y << 16);
    acc[3] += __uint_as_float(m.y & 0xffff0000u);
    acc[4] += __uint_as_float(m.z << 16);
    acc[5] += __uint_as_float(m.z & 0xffff0000u);
    acc[6] += __uint_as_float(m.w << 16);
    acc[7] += __uint_as_float(m.w & 0xffff0000u);
}

__device__ __forceinline__ void init_bf8(float* acc, uint4 m) {
    acc[0] = __uint_as_float(m.x << 16);
    acc[1] = __uint_as_float(m.x & 0xffff0000u);
    acc[2] = __uint_as_float(m.y << 16);
    acc[3] = __uint_as_float(m.y & 0xffff0000u);
    acc[4] = __uint_as_float(m.z << 16);
    acc[5] = __uint_as_float(m.z & 0xffff0000u);
    acc[6] = __uint_as_float(m.w << 16);
    acc[7] = __uint_as_float(m.w & 0xffff0000u);
}

// acc += s * unpack(m)
__device__ __forceinline__ void fma_bf8(float* acc, uint4 m, float s) {
    acc[0] = fmaf(s, __uint_as_float(m.x << 16), acc[0]);
    acc[1] = fmaf(s, __uint_as_float(m.x & 0xffff0000u), acc[1]);
    acc[2] = fmaf(s, __uint_as_float(m.y << 16), acc[2]);
    acc[3] = fmaf(s, __uint_as_float(m.y & 0xffff0000u), acc[3]);
    acc[4] = fmaf(s, __uint_as_float(m.z << 16), acc[4]);
    acc[5] = fmaf(s, __uint_as_float(m.z & 0xffff0000u), acc[5]);
    acc[6] = fmaf(s, __uint_as_float(m.w << 16), acc[6]);
    acc[7] = fmaf(s, __uint_as_float(m.w & 0xffff0000u), acc[7]);
}

// 4-deep pipelined neighbor accumulation (unscaled); STRIDE = row stride in uint4
template<int STRIDE>
__device__ __forceinline__ void gather_pipe4(const uint4* __restrict__ tsv,
                                             const int* __restrict__ csr,
                                             int beg, int end, int q, float* acc) {
    int j = beg;
    if (j + 3 < end) {
        int c0 = csr[j], c1 = csr[j + 1], c2 = csr[j + 2], c3 = csr[j + 3];
        j += 4;
        for (; j + 3 < end; j += 4) {
            int n0 = csr[j], n1 = csr[j + 1], n2 = csr[j + 2], n3 = csr[j + 3];
            uint4 m0 = tsv[c0 * STRIDE + q];
            uint4 m1 = tsv[c1 * STRIDE + q];
            uint4 m2 = tsv[c2 * STRIDE + q];
            uint4 m3 = tsv[c3 * STRIDE + q];
            add_bf8(acc, m0); add_bf8(acc, m1); add_bf8(acc, m2); add_bf8(acc, m3);
            c0 = n0; c1 = n1; c2 = n2; c3 = n3;
        }
        uint4 m0 = tsv[c0 * STRIDE + q];
        uint4 m1 = tsv[c1 * STRIDE + q];
        uint4 m2 = tsv[c2 * STRIDE + q];
        uint4 m3 = tsv[c3 * STRIDE + q];
        add_bf8(acc, m0); add_bf8(acc, m1); add_bf8(acc, m2); add_bf8(acc, m3);
    }
    for (; j < end; ++j) add_bf8(acc, tsv[csr[j] * STRIDE + q]);
}

// 4-deep pipelined, per-neighbor dis scale (fused64 layer-1 gather; STRIDE=8 fixed)
__device__ __forceinline__ void gather_pipe4s(const uint4* __restrict__ tsv,
                                              const int* __restrict__ csr,
                                              const float* __restrict__ dis,
                                              int beg, int end, int q, float* acc) {
    int j = beg;
    if (j + 3 < end) {
        int c0 = csr[j], c1 = csr[j + 1], c2 = csr[j + 2], c3 = csr[j + 3];
        j += 4;
        for (; j + 3 < end; j += 4) {
            int n0 = csr[j], n1 = csr[j + 1], n2 = csr[j + 2], n3 = csr[j + 3];
            float d0 = dis[c0], d1 = dis[c1], d2 = dis[c2], d3 = dis[c3];
            uint4 m0 = tsv[c0 * 8 + q];
            uint4 m1 = tsv[c1 * 8 + q];
            uint4 m2 = tsv[c2 * 8 + q];
            uint4 m3 = tsv[c3 * 8 + q];
            fma_bf8(acc, m0, d0); fma_bf8(acc, m1, d1);
            fma_bf8(acc, m2, d2); fma_bf8(acc, m3, d3);
            c0 = n0; c1 = n1; c2 = n2; c3 = n3;
        }
        float d0 = dis[c0], d1 = dis[c1], d2 = dis[c2], d3 = dis[c3];
        uint4 m0 = tsv[c0 * 8 + q];
        uint4 m1 = tsv[c1 * 8 + q];
        uint4 m2 = tsv[c2 * 8 + q];
        uint4 m3 = tsv[c3 * 8 + q];
        fma_bf8(acc, m0, d0); fma_bf8(acc, m1, d1);
        fma_bf8(acc, m2, d2); fma_bf8(acc, m3, d3);
    }
    for (; j < end; ++j) { int u = csr[j]; fma_bf8(acc, tsv[u * 8 + q], dis[u]); }
}

// ---------------- fused: gather64 (dis[u]-scaled, 8 thr/node) -> LDS h -> MFMA GEMM2 --------
__global__ __launch_bounds__(256) void fused64_kernel(const int* __restrict__ rowbeg,
                                                      const int* __restrict__ rowend,
                                                      const int* __restrict__ csr,
                                                      const ushort* __restrict__ ts,
                                                      const float* __restrict__ dis,
                                                      const float* __restrict__ b1,
                                                      const ushort* __restrict__ Wb2,
                                                      ushort* __restrict__ Y, int n) {
    __shared__ ushort hs[32][72];   // 144 B row stride
    const int t = threadIdx.x;
    const int vloc = t >> 3, q = t & 7;
    const int v = blockIdx.x * 32 + vloc;

    if (v < n) {
        const uint4* tsv = (const uint4*)ts;
        int beg = rowbeg[v], end = rowend[v];
        float dv = dis[v];
        float acc[8] = {0.f, 0.f, 0.f, 0.f, 0.f, 0.f, 0.f, 0.f};
        fma_bf8(acc, tsv[(long long)v * 8 + q], dv);   // self-loop: dis[v]*ts1[v]
        gather_pipe4s(tsv, csr, dis, beg, end, q, acc);

        float4 b0 = ((const float4*)b1)[q * 2];
        float4 bb = ((const float4*)b1)[q * 2 + 1];
        float r0 = fmaxf(acc[0] * dv + b0.x, 0.0f);
        float r1 = fmaxf(acc[1] * dv + b0.y, 0.0f);
        float r2 = fmaxf(acc[2] * dv + b0.z, 0.0f);
        float r3 = fmaxf(acc[3] * dv + b0.w, 0.0f);
        float r4 = fmaxf(acc[4] * dv + bb.x, 0.0f);
        float r5 = fmaxf(acc[5] * dv + bb.y, 0.0f);
        float r6 = fmaxf(acc[6] * dv + bb.z, 0.0f);
        float r7 = fmaxf(acc[7] * dv + bb.w, 0.0f);
        uint4 o;
        o.x = ((uint)f2bf(r1) << 16) | f2bf(r0);
        o.y = ((uint)f2bf(r3) << 16) | f2bf(r2);
        o.z = ((uint)f2bf(r5) << 16) | f2bf(r4);
        o.w = ((uint)f2bf(r7) << 16) | f2bf(r6);
        *(uint4*)&hs[vloc][q * 8] = o;
    } else {
        uint4 z = {0u, 0u, 0u, 0u};
        *(uint4*)&hs[vloc][q * 8] = z;
    }
    __syncthreads();

    if (t < 128) {
        const int wave = t >> 6;           // 0 or 1 -> 16-node tile
        const int lane = t & 63;
        const int la = lane & 15, fg = lane >> 4;
        bf16x8 a0 = *(const bf16x8*)&hs[wave * 16 + la][fg * 8];
        bf16x8 a1 = *(const bf16x8*)&hs[wave * 16 + la][32 + fg * 8];

        const bf16x8* wb = (const bf16x8*)Wb2;
        f32x4 dacc[3];
#pragma unroll
        for (int ct = 0; ct < 3; ++ct)
#pragma unroll
            for (int r = 0; r < 4; ++r) dacc[ct][r] = 0.0f;
#pragma unroll
        for (int ct = 0; ct < 3; ++ct) {
            dacc[ct] = __builtin_amdgcn_mfma_f32_16x16x32_bf16(a0, wb[ct * 64 + lane], dacc[ct], 0, 0, 0);
            dacc[ct] = __builtin_amdgcn_mfma_f32_16x16x32_bf16(a1, wb[(3 + ct) * 64 + lane], dacc[ct], 0, 0, 0);
        }

        const int rbase = blockIdx.x * 32 + wave * 16 + fg * 4;
#pragma unroll
        for (int r = 0; r < 4; ++r) {
            int row = rbase + r;
            if (row < n) {
                float dvr = dis[row];
#pragma unroll
                for (int ct = 0; ct < 3; ++ct)
                    Y[(long long)row * 64 + ct * 16 + la] = f2bf(dacc[ct][r] * dvr);
            }
        }
    }
}

// ---------------- fused gather 40 + log_softmax: block=320 (64 nodes), 4-deep pipeline --------
__global__ __launch_bounds__(320) void gather40ls_kernel(const int* __restrict__ rowbeg,
                                                         const int* __restrict__ rowend,
                                                         const int* __restrict__ csr,
                                                         const ushort* __restrict__ ts,
                                                         const float* __restrict__ dis,
                                                         const float* __restrict__ b,
                                                         float* __restrict__ out, int n) {
    __shared__ float smax[64][5];
    __shared__ float ssum[64][5];
    const int t = threadIdx.x;
    const int vloc = t / 5, q = t - vloc * 5;
    const int v = blockIdx.x * 64 + vloc;
    const bool active = (v < n);

    float r[8];
    if (active) {
        const uint4* tsv = (const uint4*)ts;   // row stride 64 bf16 = 8 uint4
        int beg = rowbeg[v], end = rowend[v];
        float acc[8];
        init_bf8(acc, tsv[(long long)v * 8 + q]);
        gather_pipe4<8>(tsv, csr, beg, end, q, acc);

        float dv = dis[v];
        float4 b0 = ((const float4*)b)[q * 2];
        float4 b1 = ((const float4*)b)[q * 2 + 1];
        r[0] = acc[0] * dv + b0.x;
        r[1] = acc[1] * dv + b0.y;
        r[2] = acc[2] * dv + b0.z;
        r[3] = acc[3] * dv + b0.w;
        r[4] = acc[4] * dv + b1.x;
        r[5] = acc[5] * dv + b1.y;
        r[6] = acc[6] * dv + b1.z;
        r[7] = acc[7] * dv + b1.w;
    } else {
#pragma unroll
        for (int i = 0; i < 8; ++i) r[i] = 0.0f;
    }

    float m = r[0];
#pragma unroll
    for (int i = 1; i < 8; ++i) m = fmaxf(m, r[i]);
    smax[vloc][q] = m;
    __syncthreads();
    float gm = fmaxf(fmaxf(fmaxf(smax[vloc][0], smax[vloc][1]), fmaxf(smax[vloc][2], smax[vloc][3])),
                     smax[vloc][4]);
    float s = 0.0f;
#pragma unroll
    for (int i = 0; i < 8; ++i) s += __expf(r[i] - gm);
    ssum[vloc][q] = s;
    __syncthreads();
    float tot = ssum[vloc][0] + ssum[vloc][1] + ssum[vloc][2] + ssum[vloc][3] + ssum[vloc][4];
    float c = gm + __logf(tot);

    if (active) {
        float* rp = out + (long long)v * OUT_DIM + q * 8;
        float4 o0 = { r[0] - c, r[1] - c, r[2] - c, r[3] - c };
        float4 o1 = { r[4] - c, r[5] - c, r[6] - c, r[7] - c };
        ((float4*)rp)[0] = o0;
        ((float4*)rp)[1] = o1;
    }
}

extern "C" void kernel_launch(void* const* d_in, const int* in_sizes, int n_in,
                              void* d_out, int out_size, void* d_ws, size_t ws_size,
                              hipStream_t stream) {
    const float* x  = (const float*)d_in[0];
    const int*   ei = (const int*)d_in[1];
    const float* W1 = (const float*)d_in[2];
    const float* b1 = (const float*)d_in[3];
    const float* W2 = (const float*)d_in[4];
    const float* b2 = (const float*)d_in[5];
    float* out = (float*)d_out;

    const int* src = ei;
    const int* dst = ei + N_EDGES;

    // workspace layout (bytes) — non-overlapping; csr/buk CAP-padded (196*12288*4 = 9.63 MB)
    char* ws = (char*)d_ws;
    int*    rowbeg  = (int*)ws;                         // [0, 400K)
    int*    rowend  = (int*)(ws + (512 << 10));         // [512K, +400K)
    float*  dis     = (float*)(ws + (1024 << 10));      // [1024K, +400K)
    int*    cursorA = (int*)(ws + (1536 << 10));        // 784 B (RELATIVE counts)
    ushort* Wb2     = (ushort*)(ws + (1540 << 10));     // 6 KB
    int*    csr     = (int*)(ws + (2048 << 10));        // 9.63 MB
    char*   p       = ws + (12288 << 10);               // 12 MB
    ushort* ts1     = (ushort*)p;                       // 12.8 MB (bf16 [M][64], unscaled XW1)
    ushort* ts2     = (ushort*)(p + 12800000);          // 12.8 MB (bf16 [M][64], cols 0-47 used)
    uint*   buk     = (uint*)(p + 25600000);            // 9.63 MB

    // zero relative bucket cursors, then merged partA + GEMM1 + packW2 (co-scheduled)
    hipMemsetAsync(cursorA, 0, NBUK * sizeof(int), stream);
    merged_kernel<<<MERGE_BLOCKS, 256, 0, stream>>>(src, dst, cursorA, buk, W1, W2, Wb2,
                                                    x, ts1, N_NODES);

    // per-bucket CSR build
    bucket_kernel<<<NBUK, 512, 0, stream>>>(buk, cursorA, rowbeg, rowend, dis, csr, N_NODES);

    // fused: gather64 (dis-folded) + relu/bias -> LDS -> GEMM2 -> ts2 (128 B rows)
    fused64_kernel<<<(N_NODES + 31) / 32, 256, 0, stream>>>(rowbeg, rowend, csr, ts1, dis, b1,
                                                            Wb2, ts2, N_NODES);

    // layer 2 gather + log_softmax
    gather40ls_kernel<<<(N_NODES + 63) / 64, 320, 0, stream>>>(rowbeg, rowend, csr, ts2, dis,
                                                               b2, out, N_NODES);
}